// Round 13
// baseline (256.604 us; speedup 1.0000x reference)
//
#include <hip/hip_runtime.h>
#include <stdint.h>
#include <stddef.h>

#define Tq 2048
#define DM 1024

typedef unsigned short u16;
typedef __bf16 bf16x8 __attribute__((ext_vector_type(8)));
typedef float f32x4 __attribute__((ext_vector_type(4)));
typedef unsigned short u16x8 __attribute__((ext_vector_type(8)));
typedef unsigned short u16x4 __attribute__((ext_vector_type(4)));

__device__ __forceinline__ float bf2f(u16 h) {
    union { unsigned int u; float f; } c; c.u = ((unsigned int)h) << 16; return c.f;
}
__device__ __forceinline__ u16 f2bf(float f) {
    union { float f; unsigned int u; } c; c.f = f;
    unsigned int u = c.u;
    return (u16)((u + 0x7fffu + ((u >> 16) & 1u)) >> 16);  // RNE
}

// bare v_exp_f32 (2^x) — exp2f expands to the guarded __ocml sequence.
__device__ __forceinline__ float exp2_native(float x) {
    float r; asm("v_exp_f32 %0, %1" : "=v"(r) : "v"(x)); return r;
}

// async global->LDS, 16B per lane; lds base wave-uniform (HW adds lane*16)
#define GLD(gp, lp) __builtin_amdgcn_global_load_lds(                                  \
        (const __attribute__((address_space(1))) void*)(gp),                           \
        (__attribute__((address_space(3))) void*)(lp), 16, 0, 0)

// ---------------------------------------------------------------------------
// Format sniff (round-3 proven).
// ---------------------------------------------------------------------------
__device__ __forceinline__ int sniff_fp32(const u16* xs) {
    const int lane = threadIdx.x & 63;
    const u16 u = xs[lane];
    const int e = (u >> 7) & 0xFF;
    unsigned long long m = __ballot(e >= 160);
    return __popcll(m) >= 4;
}

__device__ __forceinline__ void cvt_body(const void* src, u16* dst, int i0, int fmt) {
    if (fmt) {
        const float* s = (const float*)src;
        float4 a = *(const float4*)(s + i0);
        float4 b = *(const float4*)(s + i0 + 4);
        u16x8 o;
        o[0] = f2bf(a.x); o[1] = f2bf(a.y); o[2] = f2bf(a.z); o[3] = f2bf(a.w);
        o[4] = f2bf(b.x); o[5] = f2bf(b.y); o[6] = f2bf(b.z); o[7] = f2bf(b.w);
        *(u16x8*)(dst + i0) = o;
    } else {
        *(u16x8*)(dst + i0) = *(const u16x8*)((const u16*)src + i0);
    }
}

// ---------------------------------------------------------------------------
// Fused canonicalization: x (blocks 0..4095) + 4 weights/biases (4096..6143).
// ---------------------------------------------------------------------------
__global__ void cvt_all(const void* __restrict__ x,
                        const void* s0, const void* s1, const void* s2, const void* s3,
                        const void* t0, const void* t1, const void* t2, const void* t3,
                        u16* __restrict__ xc, u16* __restrict__ dstW, float* __restrict__ dstB,
                        const u16* __restrict__ xs, int* flag) {
    const int fmt = sniff_fp32(xs);
    int bx = blockIdx.x;
    if (bx < 4096) {
        if (bx == 0 && threadIdx.x == 0) *flag = fmt;
        const int i0 = (bx * 256 + threadIdx.x) * 8;
        cvt_body(x, xc, i0, fmt);
    } else {
        bx -= 4096;
        const int wsel = bx >> 9;          // 0..3
        const int bi   = bx & 511;
        const void* s = (wsel == 0) ? s0 : (wsel == 1) ? s1 : (wsel == 2) ? s2 : s3;
        u16* d = dstW + (size_t)wsel * (DM * DM);
        const int i0 = (bi * 256 + threadIdx.x) * 8;
        cvt_body(s, d, i0, fmt);
        if (bi == 0) {                     // bias piggybacked
            const void* bs = (wsel == 0) ? t0 : (wsel == 1) ? t1 : (wsel == 2) ? t2 : t3;
            float* db = dstB + (size_t)wsel * DM;
            const int j0 = threadIdx.x * 4;
            if (fmt) {
                *(float4*)(db + j0) = *(const float4*)((const float*)bs + j0);
            } else {
                const u16* ss = (const u16*)bs;
                db[j0+0] = bf2f(ss[j0+0]); db[j0+1] = bf2f(ss[j0+1]);
                db[j0+2] = bf2f(ss[j0+2]); db[j0+3] = bf2f(ss[j0+3]);
            }
        }
    }
}

#define NT 16   // K / 64

// ---------------------------------------------------------------------------
// GEMM v6 (round 12, PROVEN BEST: 68.0 µs mode-0 per counters): triple-buffer
// T3 interleave with ONE __syncthreads per K-tile. Untouched this round.
// Lessons ledger: counted-vmcnt+raw-barrier regressed (r11, 84 µs); 256²
// acc[8][4] spills (r10); two barriers/iter redundant (r12 fix).
// ---------------------------------------------------------------------------
__global__ __launch_bounds__(512, 1) void gemm256(
    const u16* __restrict__ A,
    const u16* __restrict__ W0, const u16* __restrict__ W1, const u16* __restrict__ W2,
    const float* __restrict__ b0, const float* __restrict__ b1, const float* __restrict__ b2,
    u16* o0, u16* o1, u16* o2,
    const int* __restrict__ flag, int mode)
{
    __shared__ u16 LB[3][24576];   // per buf: A [0,8192) elems (128x64), B [8192,24576) (256x64)

    const int K = DM;
    const int j = blockIdx.y;
    const int which = (mode == 0) ? (j >> 2) : 0;
    const u16* Wp     = (which == 0) ? W0 : (which == 1) ? W1 : W2;
    const float* bias = (which == 0) ? b0 : (which == 1) ? b1 : b2;
    u16* out          = (which == 0) ? o0 : (which == 1) ? o1 : o2;
    const int jn = (mode == 0) ? (j & 3) : j;
    const int m0 = blockIdx.x * 128, n0 = jn * 256;

    const int tid  = threadIdx.x;
    const int w    = tid >> 6, lane = tid & 63;
    const int wm   = w >> 2, wn = w & 3;
    const int l4   = lane & 15, quad = lane >> 4;
    const int rsub = lane >> 3;                       // 0..7
    const int colE = ((lane & 7) ^ rsub) << 3;        // swizzled source column (elems)

#define STAGE_A(kt, bf) do {                                                            \
        const int k0s = (kt) * 64;                                                      \
        _Pragma("unroll")                                                               \
        for (int c = 0; c < 2; ++c) {                                                   \
            const int row = c * 64 + w * 8 + rsub;                                      \
            GLD(A + (size_t)(m0 + row) * K + k0s + colE,                                \
                (char*)&LB[bf][0] + c * 8192 + w * 1024);                               \
        }                                                                               \
        {   const int row = w * 8 + rsub;                                               \
            GLD(Wp + (size_t)(n0 + row) * K + k0s + colE,                               \
                (char*)&LB[bf][0] + 16384 + w * 1024); }                                \
    } while (0)
#define STAGE_B(kt, bf) do {                                                            \
        const int k0s = (kt) * 64;                                                      \
        _Pragma("unroll")                                                               \
        for (int c = 1; c < 4; ++c) {                                                   \
            const int row = c * 64 + w * 8 + rsub;                                      \
            GLD(Wp + (size_t)(n0 + row) * K + k0s + colE,                               \
                (char*)&LB[bf][0] + 16384 + c * 8192 + w * 1024);                       \
        }                                                                               \
    } while (0)

    f32x4 acc[4][4] = {};

    STAGE_A(0, 0); STAGE_B(0, 0);
    STAGE_A(1, 1); STAGE_B(1, 1);
    __syncthreads();

    for (int t = 0; t < NT; ++t) {
        const int cur = t % 3;
        const int nxt = (t + 2) % 3;
        const u16* Ab = &LB[cur][0];
        const u16* Bb = &LB[cur][8192];
        const int swz = (l4 & 7) << 3;
        const bool pf = (t + 2 < NT);

        if (pf) STAGE_A(t + 2, nxt);
        {
            bf16x8 af[4], bfr[4];
            const int kq = (quad * 8) ^ swz;
#pragma unroll
            for (int m = 0; m < 4; ++m)
                af[m] = *(const bf16x8*)&Ab[(wm * 64 + m * 16 + l4) * 64 + kq];
#pragma unroll
            for (int n = 0; n < 4; ++n)
                bfr[n] = *(const bf16x8*)&Bb[(wn * 64 + n * 16 + l4) * 64 + kq];
            __builtin_amdgcn_s_setprio(1);
#pragma unroll
            for (int m = 0; m < 4; ++m)
#pragma unroll
                for (int n = 0; n < 4; ++n)
                    acc[m][n] = __builtin_amdgcn_mfma_f32_16x16x32_bf16(af[m], bfr[n], acc[m][n], 0, 0, 0);
            __builtin_amdgcn_s_setprio(0);
        }

        if (pf) STAGE_B(t + 2, nxt);
        {
            bf16x8 af[4], bfr[4];
            const int kq = (32 + quad * 8) ^ swz;
#pragma unroll
            for (int m = 0; m < 4; ++m)
                af[m] = *(const bf16x8*)&Ab[(wm * 64 + m * 16 + l4) * 64 + kq];
#pragma unroll
            for (int n = 0; n < 4; ++n)
                bfr[n] = *(const bf16x8*)&Bb[(wn * 64 + n * 16 + l4) * 64 + kq];
            __builtin_amdgcn_s_setprio(1);
#pragma unroll
            for (int m = 0; m < 4; ++m)
#pragma unroll
                for (int n = 0; n < 4; ++n)
                    acc[m][n] = __builtin_amdgcn_mfma_f32_16x16x32_bf16(af[m], bfr[n], acc[m][n], 0, 0, 0);
            __builtin_amdgcn_s_setprio(0);
        }

        if (t + 1 < NT) __syncthreads();
    }
#undef STAGE_A
#undef STAGE_B

    const int ofmt = (mode == 1) ? *flag : 0;
    const float SCQ = 0.18033688011112042f;    // log2(e)/sqrt(64), folded into Q

#pragma unroll
    for (int n = 0; n < 4; ++n) {
        const int colw = n0 + wn * 64 + n * 16 + l4;
        const float bv = bias[colw];
#pragma unroll
        for (int m = 0; m < 4; ++m) {
            const int mb = m0 + wm * 64 + m * 16 + quad * 4;
            if (mode == 0) {
                const int bb = mb >> 11, t0 = mb & 2047;
                const int h = colw >> 6, d = colw & 63;
                if (which == 2) {
                    // V -> (B,H,64,T) transposed store, 4 consecutive t per 8B
                    u16x4 pk;
#pragma unroll
                    for (int reg = 0; reg < 4; ++reg) pk[reg] = f2bf(acc[m][n][reg] + bv);
                    *(u16x4*)&out[((size_t)(bb * 16 + h) * 64 + d) * 2048 + t0] = pk;
                } else {
                    const float s = (which == 0) ? SCQ : 1.0f;
#pragma unroll
                    for (int reg = 0; reg < 4; ++reg)
                        out[(size_t)((bb * 16 + h) * 2048 + (t0 + reg)) * 64 + d] =
                            f2bf((acc[m][n][reg] + bv) * s);
                }
            } else if (ofmt) {
#pragma unroll
                for (int reg = 0; reg < 4; ++reg)
                    ((float*)out)[(size_t)(mb + reg) * DM + colw] = acc[m][n][reg] + bv;
            } else {
#pragma unroll
                for (int reg = 0; reg < 4; ++reg)
                    out[(size_t)(mb + reg) * DM + colw] = f2bf(acc[m][n][reg] + bv);
            }
        }
    }
}

// ---------------------------------------------------------------------------
// Flash attention v8 (round 13) — occupancy retry of round 5 with the ROOT
// CAUSE fixed: r5 failed because __launch_bounds__(256,4) clamped VGPR to 64
// and spilled 300 MB; this uses (256,2) (no clamp; G=2 state fits ~90-110
// regs <= 128 => 4 waves/SIMD legal).
//   * 2 q-tiles/block {nb, 31-nb}, nb=0..15 -> grid (64,16) = 1024 blocks.
//   * Pl[2] + SINGLE-buffered K/V (r4-proven 2-barrier staging; r6 showed
//     dbuf was worth only ~1.5 µs) -> LDS 36.9 KB => 4 blocks/CU.
//     Occupancy 18.5% -> ~37%: attacks the latency-bound profile
//     (MfmaUtil 23 / VALUBusy 26, both idle).
//   * Work/block constant: (nb+1)+(32-nb) = 33 tiles.
//   * Keeps r9 upgrades: exp2_native, MFMA rowsums (ls, all-ones B),
//     diag-only masking, SCQ folded into Q.
// Tripwire: WRITE_SIZE must stay ~16.4 MB; growth = spill => revert to the
// r12 G=4 attn verbatim.
// ---------------------------------------------------------------------------
#define LSTR 72

__global__ __launch_bounds__(256, 2) void attn4(
    const u16* __restrict__ Qb, const u16* __restrict__ Kb, const u16* __restrict__ VT,
    const unsigned char* __restrict__ pad,
    u16* __restrict__ Y)
{
    __shared__ u16 Klds[64 * LSTR];
    __shared__ u16 Vtl [64 * LSTR];
    __shared__ u16 Pl  [2][64 * LSTR];
    __shared__ unsigned char padl[64];

    const int nb = blockIdx.y;           // 0..15
    const int bh = blockIdx.x;           // 0..63 -> XCD = bh % 8
    const int b = bh >> 4, h = bh & 15;
    const u16* Qp  = Qb + (size_t)bh * (Tq * 64);
    const u16* Kp  = Kb + (size_t)bh * (Tq * 64);
    const u16* VTp = VT + (size_t)bh * (64 * Tq);

    const int tid = threadIdx.x;
    const int w = tid >> 6, lane = tid & 63;
    const int l4 = lane & 15, quad = lane >> 4;

    const int qt[2] = { nb, 31 - nb };   // ascending; covers 0..31 over nb

    bf16x8 qf[2][2];
#pragma unroll
    for (int g = 0; g < 2; ++g) {
        const u16* r = Qp + (size_t)(qt[g] * 64 + w * 16 + l4) * 64 + quad * 8;
        qf[g][0] = *(const bf16x8*)r;
        qf[g][1] = *(const bf16x8*)(r + 32);
    }

    bf16x8 ones;
#pragma unroll
    for (int e = 0; e < 8; ++e) ones[e] = (__bf16)1.0f;

    f32x4 o[2][4] = {};
    f32x4 ls[2] = {};                    // rowsums via MFMA (all cols equal)

    const int srow = tid >> 2;
    const int sc   = (tid & 3) * 16;

    u16x8 kr0, kr1, vr0, vr1; unsigned char pr = 0;
    {   // tile 0 -> regs
        const u16* kg = Kp + (size_t)srow * 64 + sc;
        kr0 = *(const u16x8*)kg; kr1 = *(const u16x8*)(kg + 8);
        const u16* vg = VTp + (size_t)srow * Tq + sc;
        vr0 = *(const u16x8*)vg; vr1 = *(const u16x8*)(vg + 8);
        if (tid < 64) pr = pad[(size_t)b * Tq + tid];
    }

    const int ktmax = qt[1];

    for (int kt = 0; kt <= ktmax; ++kt) {
        const int k0 = kt * 64;
        __syncthreads();                       // prev PV done with Klds/Vtl
        *(u16x8*)&Klds[srow * LSTR + sc]     = kr0;
        *(u16x8*)&Klds[srow * LSTR + sc + 8] = kr1;
        *(u16x8*)&Vtl [srow * LSTR + sc]     = vr0;
        *(u16x8*)&Vtl [srow * LSTR + sc + 8] = vr1;
        if (tid < 64) padl[tid] = pr;
        __syncthreads();                       // staging visible
        if (kt < ktmax) {                      // prefetch next tile into regs
            const u16* kg = Kp + (size_t)(k0 + 64 + srow) * 64 + sc;
            kr0 = *(const u16x8*)kg; kr1 = *(const u16x8*)(kg + 8);
            const u16* vg = VTp + (size_t)srow * Tq + k0 + 64 + sc;
            vr0 = *(const u16x8*)vg; vr1 = *(const u16x8*)(vg + 8);
            if (tid < 64) pr = pad[(size_t)b * Tq + k0 + 64 + tid];
        }

        const bool anypad = __any((int)(padl[lane] != 0));   // wave-uniform

        // ---- QK^T for active groups; kf shared across groups ----
        bf16x8 kf[2][4];
#pragma unroll
        for (int c = 0; c < 2; ++c)
#pragma unroll
            for (int n = 0; n < 4; ++n)
                kf[c][n] = *(const bf16x8*)&Klds[(n * 16 + l4) * LSTR + c * 32 + quad * 8];

#pragma unroll
        for (int g = 0; g < 2; ++g) {
            if (kt > qt[g]) continue;          // wave-uniform branch
            f32x4 sacc[4] = {};
            __builtin_amdgcn_s_setprio(1);
#pragma unroll
            for (int c = 0; c < 2; ++c)
#pragma unroll
                for (int n = 0; n < 4; ++n)
                    sacc[n] = __builtin_amdgcn_mfma_f32_16x16x32_bf16(qf[g][c], kf[c][n], sacc[n], 0, 0, 0);
            __builtin_amdgcn_s_setprio(0);
            u16* Pg = &Pl[g][0];
            if (kt == qt[g] || anypad) {       // diagonal tile or padding
                bool pm[4];
#pragma unroll
                for (int n = 0; n < 4; ++n) pm[n] = (padl[n * 16 + l4] != 0);
                const int qr = qt[g] * 64 + w * 16 + quad * 4;
#pragma unroll
                for (int r = 0; r < 4; ++r) {
#pragma unroll
                    for (int n = 0; n < 4; ++n) {
                        const int kgi = k0 + n * 16 + l4;
                        const bool msk = (kgi > qr + r) || pm[n];
                        const float p = msk ? 0.0f : exp2_native(sacc[n][r]);
                        *(__bf16*)&Pg[(w * 16 + quad * 4 + r) * LSTR + n * 16 + l4] = (__bf16)p;
                    }
                }
            } else {                            // interior, no padding
#pragma unroll
                for (int r = 0; r < 4; ++r) {
#pragma unroll
                    for (int n = 0; n < 4; ++n) {
                        const float p = exp2_native(sacc[n][r]);
                        *(__bf16*)&Pg[(w * 16 + quad * 4 + r) * LSTR + n * 16 + l4] = (__bf16)p;
                    }
                }
            }
        }

        // ---- PV (+ rowsum MFMA) for active groups; vf shared ----
        // No barrier needed: P is wave-private.
        bf16x8 vf[2][4];
#pragma unroll
        for (int c = 0; c < 2; ++c)
#pragma unroll
            for (int t = 0; t < 4; ++t)
                vf[c][t] = *(const bf16x8*)&Vtl[(t * 16 + l4) * LSTR + c * 32 + quad * 8];

#pragma unroll
        for (int g = 0; g < 2; ++g) {
            if (kt > qt[g]) continue;
            __builtin_amdgcn_s_setprio(1);
#pragma unroll
            for (int c = 0; c < 2; ++c) {
                bf16x8 pf = *(const bf16x8*)&Pl[g][(w * 16 + l4) * LSTR + c * 32 + quad * 8];
#pragma unroll
                for (int t = 0; t < 4; ++t)
                    o[g][t] = __builtin_amdgcn_mfma_f32_16x16x32_bf16(pf, vf[c][t], o[g][t], 0, 0, 0);
                ls[g] = __builtin_amdgcn_mfma_f32_16x16x32_bf16(pf, ones, ls[g], 0, 0, 0);
            }
            __builtin_amdgcn_s_setprio(0);
        }
    }

    // ls[g][r] holds the full rowsum in every lane (all-ones B): no reduce.
#pragma unroll
    for (int g = 0; g < 2; ++g)
#pragma unroll
        for (int r = 0; r < 4; ++r) {
            const float inv = 1.0f / ls[g][r];
            u16* y = Y + (size_t)(b * Tq + (qt[g] * 64 + w * 16 + quad * 4 + r)) * DM + h * 64;
#pragma unroll
            for (int t = 0; t < 4; ++t)
                *(__bf16*)&y[t * 16 + l4] = (__bf16)(o[g][t][r] * inv);
        }
}

// ---------------------------------------------------------------------------
extern "C" void kernel_launch(void* const* d_in, const int* in_sizes, int n_in,
                              void* d_out, int out_size, void* d_ws, size_t ws_size,
                              hipStream_t stream) {
    const void* x  = d_in[0];
    const unsigned char* pad = (const unsigned char*)d_in[1];
    const void* Wq = d_in[2];
    const void* bq = d_in[3];
    const void* Wk = d_in[4];
    const void* bk = d_in[5];
    const void* Wv = d_in[6];
    const void* bv = d_in[7];
    const void* Wo = d_in[8];
    const void* bo = d_in[9];
    const u16* xs = (const u16*)x;

    const size_t NEL = (size_t)8192 * 1024;
    const size_t WEL = (size_t)1024 * 1024;

    int* flag   = (int*)d_ws;
    u16* base16 = (u16*)((char*)d_ws + 256);
    u16* xc     = base16;                          // canonical x; reused as Yb
    u16* Wc     = base16 + NEL;                    // Wq,Wk,Wv,Wo
    float* bf_  = (float*)(base16 + NEL + 4*WEL);  // 4 x 1024 fp32 biases
    u16* Qb     = (u16*)(bf_ + 4096);
    u16* Kb     = Qb + NEL;
    u16* VT     = Kb + NEL;                        // (B,H,64,T) — written by gemm0
    u16* Yb     = xc;

    cvt_all<<<dim3(6144), 256, 0, stream>>>(x, Wq, Wk, Wv, Wo, bq, bk, bv, bo,
                                            xc, Wc, bf_, xs, flag);

    gemm256<<<dim3(64, 12), 512, 0, stream>>>(xc, Wc, Wc + WEL, Wc + 2*WEL,
                                              bf_, bf_ + 1024, bf_ + 2048,
                                              Qb, Kb, VT, flag, 0);
    attn4<<<dim3(64, 16), 256, 0, stream>>>(Qb, Kb, VT, pad, Yb);
    gemm256<<<dim3(64, 4), 512, 0, stream>>>(Yb, Wc + 3*WEL, Wc + 3*WEL, Wc + 3*WEL,
                                             bf_ + 3072, bf_ + 3072, bf_ + 3072,
                                             (u16*)d_out, nullptr, nullptr, flag, 1);
}

// Round 14
// 242.528 us; speedup vs baseline: 1.0580x; 1.0580x over previous
//
#include <hip/hip_runtime.h>
#include <stdint.h>
#include <stddef.h>

#define Tq 2048
#define DM 1024

typedef unsigned short u16;
typedef __bf16 bf16x8 __attribute__((ext_vector_type(8)));
typedef float f32x4 __attribute__((ext_vector_type(4)));
typedef unsigned short u16x8 __attribute__((ext_vector_type(8)));
typedef unsigned short u16x4 __attribute__((ext_vector_type(4)));

__device__ __forceinline__ float bf2f(u16 h) {
    union { unsigned int u; float f; } c; c.u = ((unsigned int)h) << 16; return c.f;
}
__device__ __forceinline__ u16 f2bf(float f) {
    union { float f; unsigned int u; } c; c.f = f;
    unsigned int u = c.u;
    return (u16)((u + 0x7fffu + ((u >> 16) & 1u)) >> 16);  // RNE
}

// bare v_exp_f32 (2^x) — exp2f expands to the guarded __ocml sequence.
__device__ __forceinline__ float exp2_native(float x) {
    float r; asm("v_exp_f32 %0, %1" : "=v"(r) : "v"(x)); return r;
}

// async global->LDS, 16B per lane; lds base wave-uniform (HW adds lane*16)
#define GLD(gp, lp) __builtin_amdgcn_global_load_lds(                                  \
        (const __attribute__((address_space(1))) void*)(gp),                           \
        (__attribute__((address_space(3))) void*)(lp), 16, 0, 0)

// ---------------------------------------------------------------------------
// Format sniff (round-3 proven).
// ---------------------------------------------------------------------------
__device__ __forceinline__ int sniff_fp32(const u16* xs) {
    const int lane = threadIdx.x & 63;
    const u16 u = xs[lane];
    const int e = (u >> 7) & 0xFF;
    unsigned long long m = __ballot(e >= 160);
    return __popcll(m) >= 4;
}

__device__ __forceinline__ void cvt_body(const void* src, u16* dst, int i0, int fmt) {
    if (fmt) {
        const float* s = (const float*)src;
        float4 a = *(const float4*)(s + i0);
        float4 b = *(const float4*)(s + i0 + 4);
        u16x8 o;
        o[0] = f2bf(a.x); o[1] = f2bf(a.y); o[2] = f2bf(a.z); o[3] = f2bf(a.w);
        o[4] = f2bf(b.x); o[5] = f2bf(b.y); o[6] = f2bf(b.z); o[7] = f2bf(b.w);
        *(u16x8*)(dst + i0) = o;
    } else {
        *(u16x8*)(dst + i0) = *(const u16x8*)((const u16*)src + i0);
    }
}

// ---------------------------------------------------------------------------
// Fused canonicalization: x (blocks 0..4095) + 4 weights/biases (4096..6143).
// ---------------------------------------------------------------------------
__global__ void cvt_all(const void* __restrict__ x,
                        const void* s0, const void* s1, const void* s2, const void* s3,
                        const void* t0, const void* t1, const void* t2, const void* t3,
                        u16* __restrict__ xc, u16* __restrict__ dstW, float* __restrict__ dstB,
                        const u16* __restrict__ xs, int* flag) {
    const int fmt = sniff_fp32(xs);
    int bx = blockIdx.x;
    if (bx < 4096) {
        if (bx == 0 && threadIdx.x == 0) *flag = fmt;
        const int i0 = (bx * 256 + threadIdx.x) * 8;
        cvt_body(x, xc, i0, fmt);
    } else {
        bx -= 4096;
        const int wsel = bx >> 9;          // 0..3
        const int bi   = bx & 511;
        const void* s = (wsel == 0) ? s0 : (wsel == 1) ? s1 : (wsel == 2) ? s2 : s3;
        u16* d = dstW + (size_t)wsel * (DM * DM);
        const int i0 = (bi * 256 + threadIdx.x) * 8;
        cvt_body(s, d, i0, fmt);
        if (bi == 0) {                     // bias piggybacked
            const void* bs = (wsel == 0) ? t0 : (wsel == 1) ? t1 : (wsel == 2) ? t2 : t3;
            float* db = dstB + (size_t)wsel * DM;
            const int j0 = threadIdx.x * 4;
            if (fmt) {
                *(float4*)(db + j0) = *(const float4*)((const float*)bs + j0);
            } else {
                const u16* ss = (const u16*)bs;
                db[j0+0] = bf2f(ss[j0+0]); db[j0+1] = bf2f(ss[j0+1]);
                db[j0+2] = bf2f(ss[j0+2]); db[j0+3] = bf2f(ss[j0+3]);
            }
        }
    }
}

#define NT 16   // K / 64

// ---------------------------------------------------------------------------
// GEMM v6 (round 12, PROVEN BEST: 68.0 µs mode-0 per counters): triple-buffer
// T3 interleave (stage tile t+2 inside the compute phases) with ONE
// __syncthreads per K-tile. Both-sides LDS swizzle: 0 bank conflicts.
// Lessons ledger: counted-vmcnt+raw-barrier regressed (r11, 84 µs — the bulk
// drain is CHEAPER than per-wave gates in this structure); 256² acc[8][4]
// spills (r10); two barriers/iter redundant (r12 fix, 70->68).
// ---------------------------------------------------------------------------
__global__ __launch_bounds__(512, 1) void gemm256(
    const u16* __restrict__ A,
    const u16* __restrict__ W0, const u16* __restrict__ W1, const u16* __restrict__ W2,
    const float* __restrict__ b0, const float* __restrict__ b1, const float* __restrict__ b2,
    u16* o0, u16* o1, u16* o2,
    const int* __restrict__ flag, int mode)
{
    __shared__ u16 LB[3][24576];   // per buf: A [0,8192) elems (128x64), B [8192,24576) (256x64)

    const int K = DM;
    const int j = blockIdx.y;
    const int which = (mode == 0) ? (j >> 2) : 0;
    const u16* Wp     = (which == 0) ? W0 : (which == 1) ? W1 : W2;
    const float* bias = (which == 0) ? b0 : (which == 1) ? b1 : b2;
    u16* out          = (which == 0) ? o0 : (which == 1) ? o1 : o2;
    const int jn = (mode == 0) ? (j & 3) : j;
    const int m0 = blockIdx.x * 128, n0 = jn * 256;

    const int tid  = threadIdx.x;
    const int w    = tid >> 6, lane = tid & 63;
    const int wm   = w >> 2, wn = w & 3;
    const int l4   = lane & 15, quad = lane >> 4;
    const int rsub = lane >> 3;                       // 0..7
    const int colE = ((lane & 7) ^ rsub) << 3;        // swizzled source column (elems)

#define STAGE_A(kt, bf) do {                                                            \
        const int k0s = (kt) * 64;                                                      \
        _Pragma("unroll")                                                               \
        for (int c = 0; c < 2; ++c) {                                                   \
            const int row = c * 64 + w * 8 + rsub;                                      \
            GLD(A + (size_t)(m0 + row) * K + k0s + colE,                                \
                (char*)&LB[bf][0] + c * 8192 + w * 1024);                               \
        }                                                                               \
        {   const int row = w * 8 + rsub;                                               \
            GLD(Wp + (size_t)(n0 + row) * K + k0s + colE,                               \
                (char*)&LB[bf][0] + 16384 + w * 1024); }                                \
    } while (0)
#define STAGE_B(kt, bf) do {                                                            \
        const int k0s = (kt) * 64;                                                      \
        _Pragma("unroll")                                                               \
        for (int c = 1; c < 4; ++c) {                                                   \
            const int row = c * 64 + w * 8 + rsub;                                      \
            GLD(Wp + (size_t)(n0 + row) * K + k0s + colE,                               \
                (char*)&LB[bf][0] + 16384 + c * 8192 + w * 1024);                       \
        }                                                                               \
    } while (0)

    f32x4 acc[4][4] = {};

    STAGE_A(0, 0); STAGE_B(0, 0);
    STAGE_A(1, 1); STAGE_B(1, 1);
    __syncthreads();

    for (int t = 0; t < NT; ++t) {
        const int cur = t % 3;
        const int nxt = (t + 2) % 3;
        const u16* Ab = &LB[cur][0];
        const u16* Bb = &LB[cur][8192];
        const int swz = (l4 & 7) << 3;
        const bool pf = (t + 2 < NT);

        if (pf) STAGE_A(t + 2, nxt);
        {
            bf16x8 af[4], bfr[4];
            const int kq = (quad * 8) ^ swz;
#pragma unroll
            for (int m = 0; m < 4; ++m)
                af[m] = *(const bf16x8*)&Ab[(wm * 64 + m * 16 + l4) * 64 + kq];
#pragma unroll
            for (int n = 0; n < 4; ++n)
                bfr[n] = *(const bf16x8*)&Bb[(wn * 64 + n * 16 + l4) * 64 + kq];
            __builtin_amdgcn_s_setprio(1);
#pragma unroll
            for (int m = 0; m < 4; ++m)
#pragma unroll
                for (int n = 0; n < 4; ++n)
                    acc[m][n] = __builtin_amdgcn_mfma_f32_16x16x32_bf16(af[m], bfr[n], acc[m][n], 0, 0, 0);
            __builtin_amdgcn_s_setprio(0);
        }

        if (pf) STAGE_B(t + 2, nxt);
        {
            bf16x8 af[4], bfr[4];
            const int kq = (32 + quad * 8) ^ swz;
#pragma unroll
            for (int m = 0; m < 4; ++m)
                af[m] = *(const bf16x8*)&Ab[(wm * 64 + m * 16 + l4) * 64 + kq];
#pragma unroll
            for (int n = 0; n < 4; ++n)
                bfr[n] = *(const bf16x8*)&Bb[(wn * 64 + n * 16 + l4) * 64 + kq];
            __builtin_amdgcn_s_setprio(1);
#pragma unroll
            for (int m = 0; m < 4; ++m)
#pragma unroll
                for (int n = 0; n < 4; ++n)
                    acc[m][n] = __builtin_amdgcn_mfma_f32_16x16x32_bf16(af[m], bfr[n], acc[m][n], 0, 0, 0);
            __builtin_amdgcn_s_setprio(0);
        }

        if (t + 1 < NT) __syncthreads();
    }
#undef STAGE_A
#undef STAGE_B

    const int ofmt = (mode == 1) ? *flag : 0;
    const float SCQ = 0.18033688011112042f;    // log2(e)/sqrt(64), folded into Q

#pragma unroll
    for (int n = 0; n < 4; ++n) {
        const int colw = n0 + wn * 64 + n * 16 + l4;
        const float bv = bias[colw];
#pragma unroll
        for (int m = 0; m < 4; ++m) {
            const int mb = m0 + wm * 64 + m * 16 + quad * 4;
            if (mode == 0) {
                const int bb = mb >> 11, t0 = mb & 2047;
                const int h = colw >> 6, d = colw & 63;
                if (which == 2) {
                    // V -> (B,H,64,T) transposed store, 4 consecutive t per 8B
                    u16x4 pk;
#pragma unroll
                    for (int reg = 0; reg < 4; ++reg) pk[reg] = f2bf(acc[m][n][reg] + bv);
                    *(u16x4*)&out[((size_t)(bb * 16 + h) * 64 + d) * 2048 + t0] = pk;
                } else {
                    const float s = (which == 0) ? SCQ : 1.0f;
#pragma unroll
                    for (int reg = 0; reg < 4; ++reg)
                        out[(size_t)((bb * 16 + h) * 2048 + (t0 + reg)) * 64 + d] =
                            f2bf((acc[m][n][reg] + bv) * s);
                }
            } else if (ofmt) {
#pragma unroll
                for (int reg = 0; reg < 4; ++reg)
                    ((float*)out)[(size_t)(mb + reg) * DM + colw] = acc[m][n][reg] + bv;
            } else {
#pragma unroll
                for (int reg = 0; reg < 4; ++reg)
                    out[(size_t)(mb + reg) * DM + colw] = f2bf(acc[m][n][reg] + bv);
            }
        }
    }
}

// ---------------------------------------------------------------------------
// Flash attention v7 (round 12, PROVEN BEST: 67.7 µs per counters): G=4
// q-tiles {n,n+8,23-n,31-n}, hoisted kf/vf, Pl[4], diag-only masking, K/V
// LDS double-buffer (1 staging barrier/kt), SCQ folded into Q, exp2_native,
// MFMA rowsums via all-ones B (no shuffle reduce), __launch_bounds__(256,2).
// Lessons ledger (occupancy lever CLOSED): r3 Pl[2]-pipeline spilled; r5
// (256,4) VGPR-clamped to 64 -> 300 MB spill; r13 G=2 @ (256,2) had no
// spill but occupancy only +6.5pts while staging traffic doubled (FETCH
// 26->36 MB, conflicts 4.8->7.5M) -> 76 µs. G=4 @ 2 blocks/CU maximizes
// the reuse x occupancy product for this structure.
// ---------------------------------------------------------------------------
#define LSTR 72

__global__ __launch_bounds__(256, 2) void attn4(
    const u16* __restrict__ Qb, const u16* __restrict__ Kb, const u16* __restrict__ VT,
    const unsigned char* __restrict__ pad,
    u16* __restrict__ Y)
{
    __shared__ u16 Klds[2][64 * LSTR];
    __shared__ u16 Vtl [2][64 * LSTR];
    __shared__ u16 Pl  [4][64 * LSTR];
    __shared__ unsigned char padl[2][64];

    const int nb = blockIdx.y;           // 0..7
    const int bh = blockIdx.x;           // 0..63 -> XCD = bh % 8
    const int b = bh >> 4, h = bh & 15;
    const u16* Qp  = Qb + (size_t)bh * (Tq * 64);
    const u16* Kp  = Kb + (size_t)bh * (Tq * 64);
    const u16* VTp = VT + (size_t)bh * (64 * Tq);

    const int tid = threadIdx.x;
    const int w = tid >> 6, lane = tid & 63;
    const int l4 = lane & 15, quad = lane >> 4;

    const int qt[4] = { nb, nb + 8, 23 - nb, 31 - nb };   // ascending

    bf16x8 qf[4][2];
#pragma unroll
    for (int g = 0; g < 4; ++g) {
        const u16* r = Qp + (size_t)(qt[g] * 64 + w * 16 + l4) * 64 + quad * 8;
        qf[g][0] = *(const bf16x8*)r;
        qf[g][1] = *(const bf16x8*)(r + 32);
    }

    bf16x8 ones;
#pragma unroll
    for (int e = 0; e < 8; ++e) ones[e] = (__bf16)1.0f;

    f32x4 o[4][4] = {};
    f32x4 ls[4] = {};                    // rowsums via MFMA (all cols equal)

    const int srow = tid >> 2;
    const int sc   = (tid & 3) * 16;

    u16x8 kr0, kr1, vr0, vr1; unsigned char pr = 0;
    {
        const u16* kg = Kp + (size_t)srow * 64 + sc;
        kr0 = *(const u16x8*)kg; kr1 = *(const u16x8*)(kg + 8);
        const u16* vg = VTp + (size_t)srow * Tq + sc;
        vr0 = *(const u16x8*)vg; vr1 = *(const u16x8*)(vg + 8);
        if (tid < 64) pr = pad[(size_t)b * Tq + tid];
    }
    *(u16x8*)&Klds[0][srow * LSTR + sc]     = kr0;
    *(u16x8*)&Klds[0][srow * LSTR + sc + 8] = kr1;
    *(u16x8*)&Vtl [0][srow * LSTR + sc]     = vr0;
    *(u16x8*)&Vtl [0][srow * LSTR + sc + 8] = vr1;
    if (tid < 64) padl[0][tid] = pr;

    const int ktmax = qt[3];

    for (int kt = 0; kt <= ktmax; ++kt) {
        const int cur = kt & 1;
        const int k0 = kt * 64;
        __syncthreads();                       // buf[cur] visible; prev reads done
        if (kt < ktmax) {                      // prefetch next tile into regs
            const u16* kg = Kp + (size_t)(k0 + 64 + srow) * 64 + sc;
            kr0 = *(const u16x8*)kg; kr1 = *(const u16x8*)(kg + 8);
            const u16* vg = VTp + (size_t)srow * Tq + k0 + 64 + sc;
            vr0 = *(const u16x8*)vg; vr1 = *(const u16x8*)(vg + 8);
            if (tid < 64) pr = pad[(size_t)b * Tq + k0 + 64 + tid];
        }

        const bool anypad = __any((int)(padl[cur][lane] != 0));   // wave-uniform

        // ---- QK^T for all active groups; kf shared across groups ----
        bf16x8 kf[2][4];
#pragma unroll
        for (int c = 0; c < 2; ++c)
#pragma unroll
            for (int n = 0; n < 4; ++n)
                kf[c][n] = *(const bf16x8*)&Klds[cur][(n * 16 + l4) * LSTR + c * 32 + quad * 8];

#pragma unroll
        for (int g = 0; g < 4; ++g) {
            if (kt > qt[g]) continue;          // wave-uniform branch
            f32x4 sacc[4] = {};
            __builtin_amdgcn_s_setprio(1);
#pragma unroll
            for (int c = 0; c < 2; ++c)
#pragma unroll
                for (int n = 0; n < 4; ++n)
                    sacc[n] = __builtin_amdgcn_mfma_f32_16x16x32_bf16(qf[g][c], kf[c][n], sacc[n], 0, 0, 0);
            __builtin_amdgcn_s_setprio(0);
            u16* Pg = &Pl[g][0];
            if (kt == qt[g] || anypad) {       // diagonal tile or padding
                bool pm[4];
#pragma unroll
                for (int n = 0; n < 4; ++n) pm[n] = (padl[cur][n * 16 + l4] != 0);
                const int qr = qt[g] * 64 + w * 16 + quad * 4;
#pragma unroll
                for (int r = 0; r < 4; ++r) {
#pragma unroll
                    for (int n = 0; n < 4; ++n) {
                        const int kgi = k0 + n * 16 + l4;
                        const bool msk = (kgi > qr + r) || pm[n];
                        const float p = msk ? 0.0f : exp2_native(sacc[n][r]);
                        *(__bf16*)&Pg[(w * 16 + quad * 4 + r) * LSTR + n * 16 + l4] = (__bf16)p;
                    }
                }
            } else {                            // interior, no padding
#pragma unroll
                for (int r = 0; r < 4; ++r) {
#pragma unroll
                    for (int n = 0; n < 4; ++n) {
                        const float p = exp2_native(sacc[n][r]);
                        *(__bf16*)&Pg[(w * 16 + quad * 4 + r) * LSTR + n * 16 + l4] = (__bf16)p;
                    }
                }
            }
        }

        // ---- PV (+ rowsum MFMA) for all active groups; vf shared ----
        // No barrier needed: P is wave-private.
        bf16x8 vf[2][4];
#pragma unroll
        for (int c = 0; c < 2; ++c)
#pragma unroll
            for (int t = 0; t < 4; ++t)
                vf[c][t] = *(const bf16x8*)&Vtl[cur][(t * 16 + l4) * LSTR + c * 32 + quad * 8];

#pragma unroll
        for (int g = 0; g < 4; ++g) {
            if (kt > qt[g]) continue;
            __builtin_amdgcn_s_setprio(1);
#pragma unroll
            for (int c = 0; c < 2; ++c) {
                bf16x8 pf = *(const bf16x8*)&Pl[g][(w * 16 + l4) * LSTR + c * 32 + quad * 8];
#pragma unroll
                for (int t = 0; t < 4; ++t)
                    o[g][t] = __builtin_amdgcn_mfma_f32_16x16x32_bf16(pf, vf[c][t], o[g][t], 0, 0, 0);
                ls[g] = __builtin_amdgcn_mfma_f32_16x16x32_bf16(pf, ones, ls[g], 0, 0, 0);
            }
            __builtin_amdgcn_s_setprio(0);
        }

        if (kt < ktmax) {                      // write-late: stage next tile
            *(u16x8*)&Klds[cur ^ 1][srow * LSTR + sc]     = kr0;
            *(u16x8*)&Klds[cur ^ 1][srow * LSTR + sc + 8] = kr1;
            *(u16x8*)&Vtl [cur ^ 1][srow * LSTR + sc]     = vr0;
            *(u16x8*)&Vtl [cur ^ 1][srow * LSTR + sc + 8] = vr1;
            if (tid < 64) padl[cur ^ 1][tid] = pr;
        }
    }

    // ls[g][r] holds the full rowsum in every lane (all-ones B): no reduce.
#pragma unroll
    for (int g = 0; g < 4; ++g)
#pragma unroll
        for (int r = 0; r < 4; ++r) {
            const float inv = 1.0f / ls[g][r];
            u16* y = Y + (size_t)(b * Tq + (qt[g] * 64 + w * 16 + quad * 4 + r)) * DM + h * 64;
#pragma unroll
            for (int t = 0; t < 4; ++t)
                *(__bf16*)&y[t * 16 + l4] = (__bf16)(o[g][t][r] * inv);
        }
}

// ---------------------------------------------------------------------------
extern "C" void kernel_launch(void* const* d_in, const int* in_sizes, int n_in,
                              void* d_out, int out_size, void* d_ws, size_t ws_size,
                              hipStream_t stream) {
    const void* x  = d_in[0];
    const unsigned char* pad = (const unsigned char*)d_in[1];
    const void* Wq = d_in[2];
    const void* bq = d_in[3];
    const void* Wk = d_in[4];
    const void* bk = d_in[5];
    const void* Wv = d_in[6];
    const void* bv = d_in[7];
    const void* Wo = d_in[8];
    const void* bo = d_in[9];
    const u16* xs = (const u16*)x;

    const size_t NEL = (size_t)8192 * 1024;
    const size_t WEL = (size_t)1024 * 1024;

    int* flag   = (int*)d_ws;
    u16* base16 = (u16*)((char*)d_ws + 256);
    u16* xc     = base16;                          // canonical x; reused as Yb
    u16* Wc     = base16 + NEL;                    // Wq,Wk,Wv,Wo
    float* bf_  = (float*)(base16 + NEL + 4*WEL);  // 4 x 1024 fp32 biases
    u16* Qb     = (u16*)(bf_ + 4096);
    u16* Kb     = Qb + NEL;
    u16* VT     = Kb + NEL;                        // (B,H,64,T) — written by gemm0
    u16* Yb     = xc;

    cvt_all<<<dim3(6144), 256, 0, stream>>>(x, Wq, Wk, Wv, Wo, bq, bk, bv, bo,
                                            xc, Wc, bf_, xs, flag);

    gemm256<<<dim3(64, 12), 512, 0, stream>>>(xc, Wc, Wc + WEL, Wc + 2*WEL,
                                              bf_, bf_ + 1024, bf_ + 2048,
                                              Qb, Kb, VT, flag, 0);
    attn4<<<dim3(64, 8), 256, 0, stream>>>(Qb, Kb, VT, pad, Yb);
    gemm256<<<dim3(64, 4), 512, 0, stream>>>(Yb, Wc + 3*WEL, Wc + 3*WEL, Wc + 3*WEL,
                                             bf_ + 3072, bf_ + 3072, bf_ + 3072,
                                             (u16*)d_out, nullptr, nullptr, flag, 1);
}